// Round 7
// baseline (109.128 us; speedup 1.0000x reference)
//
#include <hip/hip_runtime.h>

// ---------------------------------------------------------------------------
// StickyHDPHMMVI emission log-likelihood, f16 MFMA formulation:
// out[bt,k] = c0_k - 0.5 * sum_x A[bt,x] * B[k,x]
//   x-chunks c=0..127: c = h*64+d, slot s (e = h*32+s): A=S0[d][e], B=E_k[d][e]
//   c=128,129: A = mu[t],  B = -2*v_k[t]   (t = (c-128)*32 + s)
//   c=130,131: A = var[t], B = E_k[t,t]
// B lane-ordered: BG[((c*3 + j)*64 + kc*4 + g)*8 + q], k = j*16+kc, s = g*8+q
// A built in registers via v_dot2_f32_f16 from LDS-staged f16 F; mu/var from
// global (L1-resident per-lane rows). LDS = 32 KB exactly -> 5 blocks/CU.
// ---------------------------------------------------------------------------

#define BT_TOTAL 32768
#define BT_BLK 32

typedef _Float16 f16;
typedef __attribute__((ext_vector_type(8))) _Float16 f16x8;
typedef __attribute__((ext_vector_type(4))) _Float16 f16x4;
typedef __attribute__((ext_vector_type(2))) _Float16 h2;
typedef __attribute__((ext_vector_type(4))) float f32x4;

#if __has_builtin(__builtin_amdgcn_fdot2)
#define DOT2(a, b, c) __builtin_amdgcn_fdot2((a), (b), (c), false)
#else
#define DOT2(a, b, c) fmaf((float)(a)[0], (float)(b)[0], fmaf((float)(a)[1], (float)(b)[1], (c)))
#endif

__device__ __forceinline__ float digammaf_(float x){
  float r = 0.f;
  while (x < 6.f){ r -= 1.f / x; x += 1.f; }
  float xi = 1.f / x;
  float xi2 = xi * xi;
  return r + logf(x) - 0.5f * xi
         - xi2 * (0.083333333333f - xi2 * (0.0083333333333f - xi2 * 0.0039682539683f));
}

__device__ __forceinline__ float wsum64(float x){
  #pragma unroll
  for (int o = 32; o > 0; o >>= 1) x += __shfl_down(x, o);
  return x;  // valid in lane 0
}

// ---------- kernel A: per-k prep (register GJ, 1 barrier/iter) --------------
__global__ __launch_bounds__(256) void prep_kernel(
    const float* __restrict__ mu_k, const float* __restrict__ Psi,
    const float* __restrict__ nu_a, const float* __restrict__ kap_a,
    f16* __restrict__ BG, float* __restrict__ c0o)
{
  const int k = blockIdx.x;
  const int tid = threadIdx.x;
  if (k >= 33){
    const int kck = k - 32;                 // j=2 rows, kc 1..15 -> zero
    for (int i = tid; i < 4224; i += 256){
      int c = i >> 5, g = (i >> 3) & 3, q = i & 7;
      BG[(size_t)((c * 3 + 2) * 64 + kck * 4 + g) * 8 + q] = (f16)0.f;
    }
    if (tid == 0) c0o[k] = 0.f;
    return;
  }
  const int row = tid & 63;
  const int ch  = tid >> 6;        // column chunk: cols [ch*32, ch*32+32) of 128
  const int c0  = ch << 5;

  __shared__ float pr[2][128];
  __shared__ float fc[2][64];
  __shared__ float diag[64];
  __shared__ float muk[64];
  __shared__ float vpart[2][64];
  __shared__ float Ediag[64];

  float Wr[32];
  if (ch < 2){
    const float* Pg = Psi + (size_t)k * 4096 + (size_t)row * 64 + c0;
    #pragma unroll
    for (int c = 0; c < 32; ++c) Wr[c] = Pg[c];
  } else {
    #pragma unroll
    for (int c = 0; c < 32; ++c) Wr[c] = ((c0 - 64 + c) == row) ? 1.f : 0.f;
  }
  if (tid < 64) muk[tid] = mu_k[k * 64 + tid];
  if (row == 0){
    #pragma unroll
    for (int c = 0; c < 32; ++c) pr[0][c0 + c] = Wr[c];
  }
  if (ch == 0) fc[0][row] = Wr[0];
  __syncthreads();

  for (int jh = 0; jh < 2; ++jh){
    #pragma unroll
    for (int jl = 0; jl < 32; ++jl){
      const int j = jh * 32 + jl;
      const int cur = j & 1, nxt = cur ^ 1;
      float piv = pr[cur][j];
      float f = fc[cur][row] * __builtin_amdgcn_rcpf(piv);
      if (row == j && ch == 0) diag[j] = piv;
      if (row != j){
        #pragma unroll
        for (int c = 0; c < 32; ++c) Wr[c] = fmaf(-f, pr[cur][c0 + c], Wr[c]);
      }
      if (j < 63){
        if (row == j + 1){
          #pragma unroll
          for (int c = 0; c < 32; ++c) pr[nxt][c0 + c] = Wr[c];
        }
        if (jl < 31){ if (ch == jh)     fc[nxt][row] = Wr[jl + 1]; }
        else        { if (ch == jh + 1) fc[nxt][row] = Wr[0]; }
      }
      __syncthreads();
    }
  }

  const float nu = nu_a[k];
  const int j_k = k >> 4, kck = k & 15;

  if (ch >= 2){
    const int h = ch - 2;                   // e-half
    const float dinv = nu / diag[row];
    float vp = 0.f;
    #pragma unroll
    for (int c = 0; c < 32; ++c) vp = fmaf(Wr[c], muk[h * 32 + c], vp);
    vpart[h][row] = vp * dinv;
    const int cBG = h * 64 + row;           // chunk (d=row, e-half h)
    f16* dst = BG + (size_t)(cBG * 192 + j_k * 64 + kck * 4) * 8;
    #pragma unroll
    for (int v4 = 0; v4 < 4; ++v4){
      f16x8 ab;
      #pragma unroll
      for (int q = 0; q < 8; ++q){
        float val = Wr[v4 * 8 + q] * dinv;
        ab[q] = (f16)val;
        if ((h * 32 + v4 * 8 + q) == row) Ediag[row] = val;
      }
      *(f16x8*)(dst + v4 * 8) = ab;
    }
  }
  __syncthreads();

  if (tid < 64){
    const int t = tid;
    float v = vpart[0][t] + vpart[1][t];
    const int g = (t >> 3) & 3, q = t & 7;
    const int cA = 128 + (t >> 5);
    const int cB = 130 + (t >> 5);
    BG[(size_t)((cA * 3 + j_k) * 64 + kck * 4 + g) * 8 + q] = (f16)(-2.f * v);
    BG[(size_t)((cB * 3 + j_k) * 64 + kck * 4 + g) * 8 + q] = (f16)(Ediag[t]);
    float c2 = wsum64(v * muk[t]);
    float dg = wsum64(digammaf_((nu - (float)t) * 0.5f));
    float ld = wsum64(logf(diag[t]));
    if (t == 0){
      const float LN2   = 0.69314718055994531f;
      const float LN2PI = 1.83787706640934548f;
      float Elogdet = dg + 64.f * LN2 - ld;
      float cst = 0.5f * (Elogdet - 64.f * LN2PI);
      c0o[k] = cst - 0.5f * c2 - 32.f / kap_a[k];
    }
  }
}

// ---------------- kernel B: main (f16 MFMA, 32 KB LDS, 5 blk/CU) ------------
#define BUILD_AF(AF, FD, MUD)                                              \
  {                                                                        \
    h2 fp_[4];                                                             \
    _Pragma("unroll")                                                      \
    for (int r_ = 0; r_ < 4; ++r_){                                        \
      h2 p_ = { (FD)[2 * r_], (FD)[2 * r_ + 1] }; fp_[r_] = p_;            \
    }                                                                      \
    float s_[8];                                                           \
    _Pragma("unroll")                                                      \
    for (int q_ = 0; q_ < 8; ++q_){                                        \
      float a_ = (MUD) * mue[q_];                                          \
      _Pragma("unroll")                                                    \
      for (int r_ = 0; r_ < 4; ++r_) a_ = DOT2(fp_[r_], Fp[q_][r_], a_);   \
      s_[q_] = a_;                                                         \
    }                                                                      \
    _Pragma("unroll")                                                      \
    for (int q_ = 0; q_ < 8; ++q_) (AF)[q_] = (f16)s_[q_];                 \
  }

__global__ __launch_bounds__(256, 5) void main_kernel(
    const float* __restrict__ mu_t, const float* __restrict__ var_t,
    const float* __restrict__ F_t, const unsigned char* __restrict__ maskb,
    const f16* __restrict__ BG, const float* __restrict__ c0o,
    float* __restrict__ out)
{
  __shared__ __align__(16) f16 sG[BT_BLK][64][8];  // F[d][r], d^(bt&7); 32768 B

  const int tid = threadIdx.x;
  const int l = tid & 63;
  const int w = tid >> 6;
  const int g = l >> 4;
  const int kc = l & 15;
  const int xh = w >> 1;                 // x-half this wave computes
  const int bt0 = blockIdx.x * BT_BLK;
  const int btl = (w & 1) * 16 + kc;     // this lane's local A row
  const int btSw = btl & 7;

  const bool byteMask =
      __any((maskb[4 * l + 1] | maskb[4 * l + 2] | maskb[4 * l + 3]) != 0);

  // ---- stage F into LDS (coalesced, f32->f16) ----
  {
    const float4* fg = (const float4*)(F_t + (size_t)bt0 * 512);
    #pragma unroll
    for (int ii = 0; ii < 16; ++ii){
      int i = tid + ii * 256;
      float4 f = fg[i];
      int bt = i >> 7, rem = i & 127, d = rem >> 1, rb = (rem & 1) << 2;
      int dsw = d ^ (bt & 7);
      f16x4 ff = { (f16)f.x, (f16)f.y, (f16)f.z, (f16)f.w };
      *(f16x4*)&sG[bt][dsw][rb] = ff;
    }
  }
  __syncthreads();

  const float* murow = mu_t + (size_t)(bt0 + btl) * 64;   // L1-resident row

  // ---- per-lane register cache: 8 e-columns of F (f16 pairs), mu[e] ----
  const int e0 = xh * 32 + g * 8;
  h2 Fp[8][4];
  float mue[8];
  {
    f32x4 ma = *(const f32x4*)(murow + e0);
    f32x4 mb = *(const f32x4*)(murow + e0 + 4);
    #pragma unroll
    for (int q = 0; q < 8; ++q){
      f16x8 fv = *(const f16x8*)&sG[btl][(e0 + q) ^ btSw][0];
      #pragma unroll
      for (int r = 0; r < 4; ++r){ h2 p = { fv[2 * r], fv[2 * r + 1] }; Fp[q][r] = p; }
      mue[q] = (q < 4) ? ma[q & 3] : mb[q & 3];
    }
  }

  f32x4 acc0 = {0.f,0.f,0.f,0.f}, acc1 = {0.f,0.f,0.f,0.f}, acc2 = {0.f,0.f,0.f,0.f};

  const f16* bp = BG + (size_t)(xh * 64 * 192 + kc * 4 + g) * 8;

  // 2-stage pipeline registers
  f16x8 a0 = *(const f16x8*)(bp);
  f16x8 a1 = *(const f16x8*)(bp + 512);
  f16x8 a2 = *(const f16x8*)(bp + 1024);
  f16x8 c0v = *(const f16x8*)(bp + 1536);
  f16x8 c1v = *(const f16x8*)(bp + 1536 + 512);
  f16x8 c2v = *(const f16x8*)(bp + 1536 + 1024);
  bp += 3072;

  f16x8 fdA = *(const f16x8*)&sG[btl][0 ^ btSw][0];
  f16x8 fdB = *(const f16x8*)&sG[btl][1 ^ btSw][0];
  float2 mp = *(const float2*)(murow);     // {mu[d], mu[d+1]}

  for (int d = 0; d < 64; d += 2){
    float2 mpN = *(const float2*)(murow + ((d + 2) & 63));
    // ---- even d: consume stage A, refill with chunk d+2 ----
    {
      f16x8 af;
      BUILD_AF(af, fdA, mp.x);
      acc0 = __builtin_amdgcn_mfma_f32_16x16x32_f16(af, a0, acc0, 0, 0, 0);
      acc1 = __builtin_amdgcn_mfma_f32_16x16x32_f16(af, a1, acc1, 0, 0, 0);
      acc2 = __builtin_amdgcn_mfma_f32_16x16x32_f16(af, a2, acc2, 0, 0, 0);
      a0 = *(const f16x8*)(bp);
      a1 = *(const f16x8*)(bp + 512);
      a2 = *(const f16x8*)(bp + 1024);
      const int dn = (d + 2) & 63;
      fdA = *(const f16x8*)&sG[btl][dn ^ btSw][0];
    }
    // ---- odd d: consume stage B, refill with chunk d+3 ----
    {
      f16x8 af;
      BUILD_AF(af, fdB, mp.y);
      acc0 = __builtin_amdgcn_mfma_f32_16x16x32_f16(af, c0v, acc0, 0, 0, 0);
      acc1 = __builtin_amdgcn_mfma_f32_16x16x32_f16(af, c1v, acc1, 0, 0, 0);
      acc2 = __builtin_amdgcn_mfma_f32_16x16x32_f16(af, c2v, acc2, 0, 0, 0);
      c0v = *(const f16x8*)(bp + 1536);
      c1v = *(const f16x8*)(bp + 1536 + 512);
      c2v = *(const f16x8*)(bp + 1536 + 1024);
      const int dn = (d + 3) & 63;
      fdB = *(const f16x8*)&sG[btl][dn ^ btSw][0];
    }
    bp += 3072;
    mp = mpN;
  }

  // ---- ext chunks: xh=0 -> {128,129} A=mu;  xh=1 -> {130,131} A=var ----
  {
    const float* src = (xh == 0) ? murow : (var_t + (size_t)(bt0 + btl) * 64);
    #pragma unroll
    for (int m = 0; m < 2; ++m){
      int c = 128 + xh * 2 + m;
      const float* vr = src + m * 32 + g * 8;
      f32x4 va = *(const f32x4*)(vr);
      f32x4 vb = *(const f32x4*)(vr + 4);
      f16x8 af;
      #pragma unroll
      for (int r = 0; r < 4; ++r){ af[r] = (f16)va[r]; af[4 + r] = (f16)vb[r]; }
      const f16* bpe = BG + (size_t)(c * 192 + kc * 4 + g) * 8;
      f16x8 b0 = *(const f16x8*)(bpe);
      f16x8 b1 = *(const f16x8*)(bpe + 512);
      f16x8 b2 = *(const f16x8*)(bpe + 1024);
      acc0 = __builtin_amdgcn_mfma_f32_16x16x32_f16(af, b0, acc0, 0, 0, 0);
      acc1 = __builtin_amdgcn_mfma_f32_16x16x32_f16(af, b1, acc1, 0, 0, 0);
      acc2 = __builtin_amdgcn_mfma_f32_16x16x32_f16(af, b2, acc2, 0, 0, 0);
    }
  }

  // ---- cross-wave x reduce (sRed aliased into sG after barrier) ----
  __syncthreads();                         // all waves done reading sG
  float* sRedF = (float*)sG;               // [2][64][13] floats = 6656 B
  if (xh == 1){
    const int bofs = ((w - 2) * 64 + l) * 13;
    #pragma unroll
    for (int r = 0; r < 4; ++r){
      sRedF[bofs + r]     = acc0[r];
      sRedF[bofs + 4 + r] = acc1[r];
      sRedF[bofs + 8 + r] = acc2[r];
    }
  }
  __syncthreads();
  if (xh == 0){
    const int bofs = (w * 64 + l) * 13;
    #pragma unroll
    for (int r = 0; r < 4; ++r){
      acc0[r] += sRedF[bofs + r];
      acc1[r] += sRedF[bofs + 4 + r];
      acc2[r] += sRedF[bofs + 8 + r];
    }
    float c0a = c0o[kc];
    float c0b = c0o[16 + kc];
    float c0c = c0o[32];
    #pragma unroll
    for (int reg = 0; reg < 4; ++reg){
      int obt = bt0 + (w & 1) * 16 + g * 4 + reg;
      bool mk = byteMask ? (maskb[obt] != 0) : (maskb[(size_t)4 * obt] != 0);
      float* op = out + (size_t)obt * 33;
      op[kc]      = mk ? fmaf(-0.5f, acc0[reg], c0a) : 0.f;
      op[16 + kc] = mk ? fmaf(-0.5f, acc1[reg], c0b) : 0.f;
      if (kc == 0) op[32] = mk ? fmaf(-0.5f, acc2[reg], c0c) : 0.f;
    }
  }
}

// --------------------------- launch -----------------------------------------
extern "C" void kernel_launch(void* const* d_in, const int* in_sizes, int n_in,
                              void* d_out, int out_size, void* d_ws, size_t ws_size,
                              hipStream_t stream)
{
  const float* mu_t  = (const float*)d_in[0];
  const float* var_t = (const float*)d_in[1];
  const float* F_t   = (const float*)d_in[2];
  const float* mu_k  = (const float*)d_in[3];
  const float* Psi   = (const float*)d_in[4];
  const float* nu    = (const float*)d_in[5];
  const float* kap   = (const float*)d_in[6];
  const unsigned char* mask = (const unsigned char*)d_in[7];

  f16*   BG  = (f16*)d_ws;                      // 132*3*64*8 f16 = 405504 B
  float* c0o = (float*)((char*)d_ws + (size_t)132 * 3 * 64 * 8 * 2);
  float* outp = (float*)d_out;

  hipLaunchKernelGGL(prep_kernel, dim3(48), dim3(256), 0, stream,
                     mu_k, Psi, nu, kap, BG, c0o);
  hipLaunchKernelGGL(main_kernel, dim3(BT_TOTAL / BT_BLK), dim3(256), 0, stream,
                     mu_t, var_t, F_t, mask, BG, c0o, outp);
}

// Round 8
// 93.146 us; speedup vs baseline: 1.1716x; 1.1716x over previous
//
#include <hip/hip_runtime.h>

// ---------------------------------------------------------------------------
// StickyHDPHMMVI emission log-likelihood, f16 MFMA formulation:
// out[bt,k] = c0_k - 0.5 * sum_x A[bt,x] * B[k,x]
//   x-chunks c=0..127: c = h*64+d, slot s (e = h*32+s): A=S0[d][e], B=E_k[d][e]
//   c=128,129: A = mu[t],  B = -2*v_k[t]   (t = (c-128)*32 + s)
//   c=130,131: A = var[t], B = E_k[t,t]
// B lane-ordered: BG[((c*3 + j)*64 + kc*4 + g)*8 + q], k = j*16+kc, s = g*8+q
// A built in registers with packed-f16 FMA from LDS-staged f16 F + mu.
// 128-thread blocks (16 bt, 2 waves = 2 x-halves), 18 KB LDS -> ~8 blk/CU.
// ---------------------------------------------------------------------------

#define BT_TOTAL 32768
#define BT_BLK 16

typedef _Float16 f16;
typedef __attribute__((ext_vector_type(8))) _Float16 f16x8;
typedef __attribute__((ext_vector_type(4))) _Float16 f16x4;
typedef __attribute__((ext_vector_type(2))) _Float16 h2;
typedef __attribute__((ext_vector_type(4))) float f32x4;

__device__ __forceinline__ float digammaf_(float x){
  float r = 0.f;
  while (x < 6.f){ r -= 1.f / x; x += 1.f; }
  float xi = 1.f / x;
  float xi2 = xi * xi;
  return r + logf(x) - 0.5f * xi
         - xi2 * (0.083333333333f - xi2 * (0.0083333333333f - xi2 * 0.0039682539683f));
}

__device__ __forceinline__ float wsum64(float x){
  #pragma unroll
  for (int o = 32; o > 0; o >>= 1) x += __shfl_down(x, o);
  return x;  // valid in lane 0
}

// ---------- kernel A: per-k prep (register GJ, 1 barrier/iter) --------------
__global__ __launch_bounds__(256) void prep_kernel(
    const float* __restrict__ mu_k, const float* __restrict__ Psi,
    const float* __restrict__ nu_a, const float* __restrict__ kap_a,
    f16* __restrict__ BG, float* __restrict__ c0o)
{
  const int k = blockIdx.x;
  const int tid = threadIdx.x;
  if (k >= 33){
    const int kck = k - 32;                 // j=2 rows, kc 1..15 -> zero
    for (int i = tid; i < 4224; i += 256){
      int c = i >> 5, g = (i >> 3) & 3, q = i & 7;
      BG[(size_t)((c * 3 + 2) * 64 + kck * 4 + g) * 8 + q] = (f16)0.f;
    }
    if (tid == 0) c0o[k] = 0.f;
    return;
  }
  const int row = tid & 63;
  const int ch  = tid >> 6;        // column chunk: cols [ch*32, ch*32+32) of 128
  const int c0  = ch << 5;

  __shared__ float pr[2][128];
  __shared__ float fc[2][64];
  __shared__ float diag[64];
  __shared__ float muk[64];
  __shared__ float vpart[2][64];
  __shared__ float Ediag[64];

  float Wr[32];
  if (ch < 2){
    const float* Pg = Psi + (size_t)k * 4096 + (size_t)row * 64 + c0;
    #pragma unroll
    for (int c = 0; c < 32; ++c) Wr[c] = Pg[c];
  } else {
    #pragma unroll
    for (int c = 0; c < 32; ++c) Wr[c] = ((c0 - 64 + c) == row) ? 1.f : 0.f;
  }
  if (tid < 64) muk[tid] = mu_k[k * 64 + tid];
  if (row == 0){
    #pragma unroll
    for (int c = 0; c < 32; ++c) pr[0][c0 + c] = Wr[c];
  }
  if (ch == 0) fc[0][row] = Wr[0];
  __syncthreads();

  for (int jh = 0; jh < 2; ++jh){
    #pragma unroll
    for (int jl = 0; jl < 32; ++jl){
      const int j = jh * 32 + jl;
      const int cur = j & 1, nxt = cur ^ 1;
      float piv = pr[cur][j];
      float f = fc[cur][row] * __builtin_amdgcn_rcpf(piv);
      if (row == j && ch == 0) diag[j] = piv;
      if (row != j){
        #pragma unroll
        for (int c = 0; c < 32; ++c) Wr[c] = fmaf(-f, pr[cur][c0 + c], Wr[c]);
      }
      if (j < 63){
        if (row == j + 1){
          #pragma unroll
          for (int c = 0; c < 32; ++c) pr[nxt][c0 + c] = Wr[c];
        }
        if (jl < 31){ if (ch == jh)     fc[nxt][row] = Wr[jl + 1]; }
        else        { if (ch == jh + 1) fc[nxt][row] = Wr[0]; }
      }
      __syncthreads();
    }
  }

  const float nu = nu_a[k];
  const int j_k = k >> 4, kck = k & 15;

  if (ch >= 2){
    const int h = ch - 2;                   // e-half
    const float dinv = nu / diag[row];
    float vp = 0.f;
    #pragma unroll
    for (int c = 0; c < 32; ++c) vp = fmaf(Wr[c], muk[h * 32 + c], vp);
    vpart[h][row] = vp * dinv;
    const int cBG = h * 64 + row;           // chunk (d=row, e-half h)
    f16* dst = BG + (size_t)(cBG * 192 + j_k * 64 + kck * 4) * 8;
    #pragma unroll
    for (int v4 = 0; v4 < 4; ++v4){
      f16x8 ab;
      #pragma unroll
      for (int q = 0; q < 8; ++q){
        float val = Wr[v4 * 8 + q] * dinv;
        ab[q] = (f16)val;
        if ((h * 32 + v4 * 8 + q) == row) Ediag[row] = val;
      }
      *(f16x8*)(dst + v4 * 8) = ab;
    }
  }
  __syncthreads();

  if (tid < 64){
    const int t = tid;
    float v = vpart[0][t] + vpart[1][t];
    const int g = (t >> 3) & 3, q = t & 7;
    const int cA = 128 + (t >> 5);
    const int cB = 130 + (t >> 5);
    BG[(size_t)((cA * 3 + j_k) * 64 + kck * 4 + g) * 8 + q] = (f16)(-2.f * v);
    BG[(size_t)((cB * 3 + j_k) * 64 + kck * 4 + g) * 8 + q] = (f16)(Ediag[t]);
    float c2 = wsum64(v * muk[t]);
    float dg = wsum64(digammaf_((nu - (float)t) * 0.5f));
    float ld = wsum64(logf(diag[t]));
    if (t == 0){
      const float LN2   = 0.69314718055994531f;
      const float LN2PI = 1.83787706640934548f;
      float Elogdet = dg + 64.f * LN2 - ld;
      float cst = 0.5f * (Elogdet - 64.f * LN2PI);
      c0o[k] = cst - 0.5f * c2 - 32.f / kap_a[k];
    }
  }
}

// -------- kernel B: main (f16 MFMA, packed-f16 build, 128-thr blocks) -------
#define BUILD_AF(AF, FD, MUDH)                                             \
  {                                                                        \
    h2 s0_, s1_, s2_, s3_;                                                 \
    h2 mb_ = { (MUDH), (MUDH) };                                           \
    s0_ = mb_ * Me2[0]; s1_ = mb_ * Me2[1];                                \
    s2_ = mb_ * Me2[2]; s3_ = mb_ * Me2[3];                                \
    _Pragma("unroll")                                                      \
    for (int r_ = 0; r_ < 8; ++r_){                                        \
      h2 fb_ = { (FD)[r_], (FD)[r_] };                                     \
      s0_ += fb_ * Fe2[0][r_];                                             \
      s1_ += fb_ * Fe2[1][r_];                                             \
      s2_ += fb_ * Fe2[2][r_];                                             \
      s3_ += fb_ * Fe2[3][r_];                                             \
    }                                                                      \
    (AF)[0] = s0_[0]; (AF)[1] = s0_[1];                                    \
    (AF)[2] = s1_[0]; (AF)[3] = s1_[1];                                    \
    (AF)[4] = s2_[0]; (AF)[5] = s2_[1];                                    \
    (AF)[6] = s3_[0]; (AF)[7] = s3_[1];                                    \
  }

__global__ __launch_bounds__(128) void main_kernel(
    const float* __restrict__ mu_t, const float* __restrict__ var_t,
    const float* __restrict__ F_t, const unsigned char* __restrict__ maskb,
    const f16* __restrict__ BG, const float* __restrict__ c0o,
    float* __restrict__ out)
{
  __shared__ __align__(16) f16 sG[BT_BLK][64][8];  // F[d][r], d^(bt&7); 16384 B
  __shared__ __align__(16) f16 sMu[BT_BLK][64];    // block-8 d-swizzle;  2048 B

  const int tid = threadIdx.x;
  const int l = tid & 63;
  const int xh = tid >> 6;               // wave = x-half
  const int g = l >> 4;
  const int kc = l & 15;
  const int bt0 = blockIdx.x * BT_BLK;
  const int btl = kc;                    // this lane's local A row
  const int btSw = btl & 7;

  const bool byteMask =
      __any((maskb[4 * l + 1] | maskb[4 * l + 2] | maskb[4 * l + 3]) != 0);

  // ---- stage F / mu into LDS (coalesced, f32->f16) ----
  {
    const float4* fg = (const float4*)(F_t + (size_t)bt0 * 512);
    #pragma unroll
    for (int ii = 0; ii < 16; ++ii){
      int i = tid + ii * 128;
      float4 f = fg[i];
      int bt = i >> 7, rem = i & 127, d = rem >> 1, rb = (rem & 1) << 2;
      int dsw = d ^ (bt & 7);
      f16x4 ff = { (f16)f.x, (f16)f.y, (f16)f.z, (f16)f.w };
      *(f16x4*)&sG[bt][dsw][rb] = ff;
    }
    const float4* mg = (const float4*)(mu_t + (size_t)bt0 * 64);
    #pragma unroll
    for (int ii = 0; ii < 2; ++ii){
      int i = tid + ii * 128;
      float4 m4 = mg[i];
      int bt = i >> 4, d0 = (i & 15) << 2;
      int dsw = (((d0 >> 3) ^ (bt & 7)) << 3) | (d0 & 7);
      f16x4 mm = { (f16)m4.x, (f16)m4.y, (f16)m4.z, (f16)m4.w };
      *(f16x4*)&sMu[bt][dsw] = mm;
    }
  }
  __syncthreads();

  // ---- per-lane register cache: 8 e-columns of F + mu, as h2 pairs over e --
  const int e0 = xh * 32 + g * 8;
  h2 Fe2[4][8];
  h2 Me2[4];
  {
    f16x8 mrow = *(const f16x8*)&sMu[btl][((e0 >> 3) ^ btSw) << 3];
    #pragma unroll
    for (int p = 0; p < 4; ++p){
      f16x8 fa = *(const f16x8*)&sG[btl][(e0 + 2 * p) ^ btSw][0];
      f16x8 fb = *(const f16x8*)&sG[btl][(e0 + 2 * p + 1) ^ btSw][0];
      #pragma unroll
      for (int r = 0; r < 8; ++r){ h2 pp = { fa[r], fb[r] }; Fe2[p][r] = pp; }
      h2 mm = { mrow[2 * p], mrow[2 * p + 1] };
      Me2[p] = mm;
    }
  }

  f32x4 acc0 = {0.f,0.f,0.f,0.f}, acc1 = {0.f,0.f,0.f,0.f}, acc2 = {0.f,0.f,0.f,0.f};

  const f16* bp = BG + (size_t)(xh * 64 * 192 + kc * 4 + g) * 8;

  // 2-stage pipeline registers (B one chunk-pair ahead)
  f16x8 a0 = *(const f16x8*)(bp);
  f16x8 a1 = *(const f16x8*)(bp + 512);
  f16x8 a2 = *(const f16x8*)(bp + 1024);
  f16x8 c0v = *(const f16x8*)(bp + 1536);
  f16x8 c1v = *(const f16x8*)(bp + 1536 + 512);
  f16x8 c2v = *(const f16x8*)(bp + 1536 + 1024);
  bp += 3072;

  f16x8 fdA = *(const f16x8*)&sG[btl][0 ^ btSw][0];
  f16x8 fdB = *(const f16x8*)&sG[btl][1 ^ btSw][0];
  f16 mudA = sMu[btl][((0 ^ btSw) << 3) | 0];     // d=0: block 0^btSw, elem 0
  f16 mudB = sMu[btl][((0 ^ btSw) << 3) | 1];     // d=1: same block, elem 1

  for (int d = 0; d < 64; d += 2){
    // ---- even d: consume stage A, refill with chunk d+2 ----
    {
      f16x8 af;
      BUILD_AF(af, fdA, mudA);
      acc0 = __builtin_amdgcn_mfma_f32_16x16x32_f16(af, a0, acc0, 0, 0, 0);
      acc1 = __builtin_amdgcn_mfma_f32_16x16x32_f16(af, a1, acc1, 0, 0, 0);
      acc2 = __builtin_amdgcn_mfma_f32_16x16x32_f16(af, a2, acc2, 0, 0, 0);
      a0 = *(const f16x8*)(bp);
      a1 = *(const f16x8*)(bp + 512);
      a2 = *(const f16x8*)(bp + 1024);
      const int dn = (d + 2) & 63;
      fdA = *(const f16x8*)&sG[btl][dn ^ btSw][0];
      mudA = sMu[btl][((((dn >> 3) ^ btSw) << 3)) | (dn & 7)];
    }
    // ---- odd d: consume stage B, refill with chunk d+3 ----
    {
      f16x8 af;
      BUILD_AF(af, fdB, mudB);
      acc0 = __builtin_amdgcn_mfma_f32_16x16x32_f16(af, c0v, acc0, 0, 0, 0);
      acc1 = __builtin_amdgcn_mfma_f32_16x16x32_f16(af, c1v, acc1, 0, 0, 0);
      acc2 = __builtin_amdgcn_mfma_f32_16x16x32_f16(af, c2v, acc2, 0, 0, 0);
      c0v = *(const f16x8*)(bp + 1536);
      c1v = *(const f16x8*)(bp + 1536 + 512);
      c2v = *(const f16x8*)(bp + 1536 + 1024);
      const int dn = (d + 3) & 63;
      fdB = *(const f16x8*)&sG[btl][dn ^ btSw][0];
      mudB = sMu[btl][((((dn >> 3) ^ btSw) << 3)) | (dn & 7)];
    }
    bp += 3072;
  }

  // ---- ext chunks: xh=0 -> {128,129} A=mu (LDS);  xh=1 -> {130,131} A=var --
  #pragma unroll
  for (int m = 0; m < 2; ++m){
    int c = 128 + xh * 2 + m;
    f16x8 af;
    if (xh == 0){
      af = *(const f16x8*)&sMu[btl][((m * 4 + g) ^ btSw) << 3];
    } else {
      const float* vr = var_t + (size_t)(bt0 + btl) * 64 + m * 32 + g * 8;
      f32x4 va = *(const f32x4*)(vr);
      f32x4 vb = *(const f32x4*)(vr + 4);
      #pragma unroll
      for (int r = 0; r < 4; ++r){ af[r] = (f16)va[r]; af[4 + r] = (f16)vb[r]; }
    }
    const f16* bpe = BG + (size_t)(c * 192 + kc * 4 + g) * 8;
    f16x8 b0 = *(const f16x8*)(bpe);
    f16x8 b1 = *(const f16x8*)(bpe + 512);
    f16x8 b2 = *(const f16x8*)(bpe + 1024);
    acc0 = __builtin_amdgcn_mfma_f32_16x16x32_f16(af, b0, acc0, 0, 0, 0);
    acc1 = __builtin_amdgcn_mfma_f32_16x16x32_f16(af, b1, acc1, 0, 0, 0);
    acc2 = __builtin_amdgcn_mfma_f32_16x16x32_f16(af, b2, acc2, 0, 0, 0);
  }

  // ---- cross-wave x reduce (aliased into sG after barrier) ----
  __syncthreads();                         // all waves done reading sG/sMu
  float* sRedF = (float*)sG;               // [64][13] floats = 3328 B
  if (xh == 1){
    const int bofs = l * 13;
    #pragma unroll
    for (int r = 0; r < 4; ++r){
      sRedF[bofs + r]     = acc0[r];
      sRedF[bofs + 4 + r] = acc1[r];
      sRedF[bofs + 8 + r] = acc2[r];
    }
  }
  __syncthreads();
  if (xh == 0){
    const int bofs = l * 13;
    #pragma unroll
    for (int r = 0; r < 4; ++r){
      acc0[r] += sRedF[bofs + r];
      acc1[r] += sRedF[bofs + 4 + r];
      acc2[r] += sRedF[bofs + 8 + r];
    }
    float c0a = c0o[kc];
    float c0b = c0o[16 + kc];
    float c0c = c0o[32];
    #pragma unroll
    for (int reg = 0; reg < 4; ++reg){
      int obt = bt0 + g * 4 + reg;
      bool mk = byteMask ? (maskb[obt] != 0) : (maskb[(size_t)4 * obt] != 0);
      float* op = out + (size_t)obt * 33;
      op[kc]      = mk ? fmaf(-0.5f, acc0[reg], c0a) : 0.f;
      op[16 + kc] = mk ? fmaf(-0.5f, acc1[reg], c0b) : 0.f;
      if (kc == 0) op[32] = mk ? fmaf(-0.5f, acc2[reg], c0c) : 0.f;
    }
  }
}

// --------------------------- launch -----------------------------------------
extern "C" void kernel_launch(void* const* d_in, const int* in_sizes, int n_in,
                              void* d_out, int out_size, void* d_ws, size_t ws_size,
                              hipStream_t stream)
{
  const float* mu_t  = (const float*)d_in[0];
  const float* var_t = (const float*)d_in[1];
  const float* F_t   = (const float*)d_in[2];
  const float* mu_k  = (const float*)d_in[3];
  const float* Psi   = (const float*)d_in[4];
  const float* nu    = (const float*)d_in[5];
  const float* kap   = (const float*)d_in[6];
  const unsigned char* mask = (const unsigned char*)d_in[7];

  f16*   BG  = (f16*)d_ws;                      // 132*3*64*8 f16 = 405504 B
  float* c0o = (float*)((char*)d_ws + (size_t)132 * 3 * 64 * 8 * 2);
  float* outp = (float*)d_out;

  hipLaunchKernelGGL(prep_kernel, dim3(48), dim3(256), 0, stream,
                     mu_k, Psi, nu, kap, BG, c0o);
  hipLaunchKernelGGL(main_kernel, dim3(BT_TOTAL / BT_BLK), dim3(128), 0, stream,
                     mu_t, var_t, F_t, mask, BG, c0o, outp);
}

// Round 10
// 80.279 us; speedup vs baseline: 1.3594x; 1.1603x over previous
//
#include <hip/hip_runtime.h>

// ---------------------------------------------------------------------------
// StickyHDPHMMVI emission log-likelihood, f16 MFMA + symmetry formulation:
// out[bt,k] = c0_k - 0.5 * sum_x A[bt,x] * B[k,x]
// x enumerates SYMMETRIC pair-blocks (bI<=bJ) of the 64x64 (d,e) space:
//   pair pb=(bI,bJ), chunks c = pb*2+p (p=0,1), slot s = g*8+q:
//     d = bI*8 + p*4 + g, e = bJ*8 + q
//     A = S0[d][e] (mu muT + F FT),  B = E_k[d][e] * (bI<bJ ? 2 : 1)
//   c=72,73: A = mu[t],  B = -2*v_k[t]   (t = (c-72)*32 + s)
//   c=74,75: A = var[t], B = E_k[t,t]
// B lane-ordered: BG[((c*3 + j)*64 + kc*4 + g)*8 + q], k = j*16+kc
// 76 chunks total vs 132 unsymmetrized (1.74x less work).
// NOTE: ext chunks MUST be addressed absolutely (chunk 72), not via the
// pipelined bp (which overshoots to 74 after the last refill) — r9 bug.
// ---------------------------------------------------------------------------

#define BT_TOTAL 32768
#define BT_BLK 16
#define NCHUNK 76

typedef _Float16 f16;
typedef __attribute__((ext_vector_type(8))) _Float16 f16x8;
typedef __attribute__((ext_vector_type(4))) _Float16 f16x4;
typedef __attribute__((ext_vector_type(2))) _Float16 h2;
typedef __attribute__((ext_vector_type(4))) float f32x4;

#if __has_builtin(__builtin_amdgcn_fdot2)
#define DOT2(a, b, c) __builtin_amdgcn_fdot2((a), (b), (c), false)
#else
#define DOT2(a, b, c) fmaf((float)(a)[0], (float)(b)[0], fmaf((float)(a)[1], (float)(b)[1], (c)))
#endif

// pair-block tables (bJ outer 0..7, bI inner 0..bJ), +1 guard entry
__constant__ unsigned char PB_BJ[37] =
  {0, 1,1, 2,2,2, 3,3,3,3, 4,4,4,4,4, 5,5,5,5,5,5, 6,6,6,6,6,6,6, 7,7,7,7,7,7,7,7, 7};
__constant__ unsigned char PB_BI[37] =
  {0, 0,1, 0,1,2, 0,1,2,3, 0,1,2,3,4, 0,1,2,3,4,5, 0,1,2,3,4,5,6, 0,1,2,3,4,5,6,7, 7};

__device__ __forceinline__ float digammaf_(float x){
  float r = 0.f;
  while (x < 6.f){ r -= 1.f / x; x += 1.f; }
  float xi = 1.f / x;
  float xi2 = xi * xi;
  return r + logf(x) - 0.5f * xi
         - xi2 * (0.083333333333f - xi2 * (0.0083333333333f - xi2 * 0.0039682539683f));
}

__device__ __forceinline__ float wsum64(float x){
  #pragma unroll
  for (int o = 32; o > 0; o >>= 1) x += __shfl_down(x, o);
  return x;  // valid in lane 0
}

// ---------- kernel A: per-k prep (register GJ, 1 barrier/iter) --------------
__global__ __launch_bounds__(256) void prep_kernel(
    const float* __restrict__ mu_k, const float* __restrict__ Psi,
    const float* __restrict__ nu_a, const float* __restrict__ kap_a,
    f16* __restrict__ BG, float* __restrict__ c0o)
{
  const int k = blockIdx.x;
  const int tid = threadIdx.x;
  if (k >= 33){
    const int kck = k - 32;                 // j=2 rows, kc 1..15 -> zero
    for (int i = tid; i < NCHUNK * 32; i += 256){
      int c = i >> 5, s = i & 31;
      BG[(size_t)((c * 3 + 2) * 64 + kck * 4 + (s >> 3)) * 8 + (s & 7)] = (f16)0.f;
    }
    if (tid == 0) c0o[k] = 0.f;
    return;
  }
  const int row = tid & 63;
  const int ch  = tid >> 6;        // column chunk: cols [ch*32, ch*32+32) of 128
  const int c0  = ch << 5;

  __shared__ float pr[2][128];
  __shared__ float fc[2][64];
  __shared__ float diag[64];
  __shared__ float muk[64];
  __shared__ float vpart[2][64];
  __shared__ float Ediag[64];

  float Wr[32];
  if (ch < 2){
    const float* Pg = Psi + (size_t)k * 4096 + (size_t)row * 64 + c0;
    #pragma unroll
    for (int c = 0; c < 32; ++c) Wr[c] = Pg[c];
  } else {
    #pragma unroll
    for (int c = 0; c < 32; ++c) Wr[c] = ((c0 - 64 + c) == row) ? 1.f : 0.f;
  }
  if (tid < 64) muk[tid] = mu_k[k * 64 + tid];
  if (row == 0){
    #pragma unroll
    for (int c = 0; c < 32; ++c) pr[0][c0 + c] = Wr[c];
  }
  if (ch == 0) fc[0][row] = Wr[0];
  __syncthreads();

  for (int jh = 0; jh < 2; ++jh){
    #pragma unroll
    for (int jl = 0; jl < 32; ++jl){
      const int j = jh * 32 + jl;
      const int cur = j & 1, nxt = cur ^ 1;
      float piv = pr[cur][j];
      float f = fc[cur][row] * __builtin_amdgcn_rcpf(piv);
      if (row == j && ch == 0) diag[j] = piv;
      if (row != j){
        #pragma unroll
        for (int c = 0; c < 32; ++c) Wr[c] = fmaf(-f, pr[cur][c0 + c], Wr[c]);
      }
      if (j < 63){
        if (row == j + 1){
          #pragma unroll
          for (int c = 0; c < 32; ++c) pr[nxt][c0 + c] = Wr[c];
        }
        if (jl < 31){ if (ch == jh)     fc[nxt][row] = Wr[jl + 1]; }
        else        { if (ch == jh + 1) fc[nxt][row] = Wr[0]; }
      }
      __syncthreads();
    }
  }

  const float nu = nu_a[k];
  const int j_k = k >> 4, kck = k & 15;

  if (ch >= 2){
    const int h = ch - 2;                   // e-half this thread owns
    const float dinv = nu / diag[row];
    float vp = 0.f;
    #pragma unroll
    for (int c = 0; c < 32; ++c) vp = fmaf(Wr[c], muk[h * 32 + c], vp);
    vpart[h][row] = vp * dinv;
    // E-row scatter into symmetric pair-block layout (only bI <= bJ stored)
    const int d = row;
    const int bI = d >> 3;
    const int pch = (d >> 2) & 1;
    const int sHi = d & 3;                  // g-slot
    #pragma unroll
    for (int cc = 0; cc < 32; ++cc){
      const int e = h * 32 + cc;
      const int bJ = e >> 3;
      float val = Wr[cc] * dinv;
      if (e == d) Ediag[row] = val;
      if (bI <= bJ){
        const int pb = ((bJ * (bJ + 1)) >> 1) + bI;
        const int ci = pb * 2 + pch;
        const float sc = (bI < bJ) ? 2.f : 1.f;
        BG[(size_t)((ci * 3 + j_k) * 64 + kck * 4 + sHi) * 8 + (e & 7)] = (f16)(val * sc);
      }
    }
  }
  __syncthreads();

  if (tid < 64){
    const int t = tid;
    float v = vpart[0][t] + vpart[1][t];
    const int g = (t >> 3) & 3, q = t & 7;
    const int cA = 72 + (t >> 5);
    const int cB = 74 + (t >> 5);
    BG[(size_t)((cA * 3 + j_k) * 64 + kck * 4 + g) * 8 + q] = (f16)(-2.f * v);
    BG[(size_t)((cB * 3 + j_k) * 64 + kck * 4 + g) * 8 + q] = (f16)(Ediag[t]);
    float c2 = wsum64(v * muk[t]);
    float dg = wsum64(digammaf_((nu - (float)t) * 0.5f));
    float ld = wsum64(logf(diag[t]));
    if (t == 0){
      const float LN2   = 0.69314718055994531f;
      const float LN2PI = 1.83787706640934548f;
      float Elogdet = dg + 64.f * LN2 - ld;
      float cst = 0.5f * (Elogdet - 64.f * LN2PI);
      c0o[k] = cst - 0.5f * c2 - 32.f / kap_a[k];
    }
  }
}

// -------- kernel B: main (f16 MFMA, symmetric chunks, 128-thr blocks) -------
#define BUILD(AF, FD, MUD)                                                 \
  {                                                                        \
    float s_[8];                                                           \
    _Pragma("unroll")                                                      \
    for (int q_ = 0; q_ < 8; ++q_) s_[q_] = (MUD) * mue[q_];               \
    _Pragma("unroll")                                                      \
    for (int r_ = 0; r_ < 4; ++r_){                                        \
      h2 fp_ = { (FD)[2 * r_], (FD)[2 * r_ + 1] };                         \
      _Pragma("unroll")                                                    \
      for (int q_ = 0; q_ < 8; ++q_){                                      \
        h2 ep_ = { FeT[q_][2 * r_], FeT[q_][2 * r_ + 1] };                 \
        s_[q_] = DOT2(fp_, ep_, s_[q_]);                                   \
      }                                                                    \
    }                                                                      \
    _Pragma("unroll")                                                      \
    for (int q_ = 0; q_ < 8; ++q_) (AF)[q_] = (f16)s_[q_];                 \
  }

#define MFMA3(AF, B0, B1, B2)                                              \
  acc0 = __builtin_amdgcn_mfma_f32_16x16x32_f16((AF), (B0), acc0, 0, 0, 0);\
  acc1 = __builtin_amdgcn_mfma_f32_16x16x32_f16((AF), (B1), acc1, 0, 0, 0);\
  acc2 = __builtin_amdgcn_mfma_f32_16x16x32_f16((AF), (B2), acc2, 0, 0, 0);

__global__ __launch_bounds__(128) void main_kernel(
    const float* __restrict__ mu_t, const float* __restrict__ var_t,
    const float* __restrict__ F_t, const unsigned char* __restrict__ maskb,
    const f16* __restrict__ BG, const float* __restrict__ c0o,
    float* __restrict__ out)
{
  __shared__ __align__(16) f16 sG[BT_BLK][64][8];  // F[d][r], d^(bt&7); 16384 B
  __shared__ __align__(16) f16 sMu[BT_BLK][64];    // block-8 d-swizzle;  2048 B

  const int tid = threadIdx.x;
  const int l = tid & 63;
  const int xh = tid >> 6;               // wave id: chunk-range split
  const int g = l >> 4;
  const int kc = l & 15;
  const int bt0 = blockIdx.x * BT_BLK;
  const int btl = kc;                    // this lane's local A row
  const int btSw = btl & 7;

  const bool byteMask =
      __any((maskb[4 * l + 1] | maskb[4 * l + 2] | maskb[4 * l + 3]) != 0);

  // ---- stage F / mu into LDS (coalesced, f32->f16) ----
  {
    const float4* fg = (const float4*)(F_t + (size_t)bt0 * 512);
    #pragma unroll
    for (int ii = 0; ii < 16; ++ii){
      int i = tid + ii * 128;
      float4 f = fg[i];
      int bt = i >> 7, rem = i & 127, d = rem >> 1, rb = (rem & 1) << 2;
      int dsw = d ^ (bt & 7);
      f16x4 ff = { (f16)f.x, (f16)f.y, (f16)f.z, (f16)f.w };
      *(f16x4*)&sG[bt][dsw][rb] = ff;
    }
    const float4* mg = (const float4*)(mu_t + (size_t)bt0 * 64);
    #pragma unroll
    for (int ii = 0; ii < 2; ++ii){
      int i = tid + ii * 128;
      float4 m4 = mg[i];
      int bt = i >> 4, d0 = (i & 15) << 2;
      int dsw = (((d0 >> 3) ^ (bt & 7)) << 3) | (d0 & 7);
      f16x4 mm = { (f16)m4.x, (f16)m4.y, (f16)m4.z, (f16)m4.w };
      *(f16x4*)&sMu[bt][dsw] = mm;
    }
  }
  __syncthreads();

  // per-wave chunk range: wave0 = pairs [0,19), wave1 = pairs [19,36) + ext
  const int ppStart = xh ? 19 : 0;
  const int ppEnd   = xh ? 36 : 19;

  f32x4 acc0 = {0.f,0.f,0.f,0.f}, acc1 = {0.f,0.f,0.f,0.f}, acc2 = {0.f,0.f,0.f,0.f};

  f16x8 FeT[8];      // F rows e = bJ*8+q (reloaded per bJ)
  float mue[8];

  const f16* bp = BG + (size_t)(ppStart * 2) * 1536 + (size_t)(kc * 4 + g) * 8;

  // prologue: stage A = chunk 2*ppStart, stage B = chunk 2*ppStart+1
  const int bI0 = PB_BI[ppStart];
  f16x8 fdA, fdB;
  float mudA, mudB;
  {
    int dA = bI0 * 8 + g;
    int dB = bI0 * 8 + 4 + g;
    fdA = *(const f16x8*)&sG[btl][dA ^ btSw][0];
    fdB = *(const f16x8*)&sG[btl][dB ^ btSw][0];
    mudA = (float)sMu[btl][(((dA >> 3) ^ btSw) << 3) | (dA & 7)];
    mudB = (float)sMu[btl][(((dB >> 3) ^ btSw) << 3) | (dB & 7)];
  }
  f16x8 a0 = *(const f16x8*)(bp);
  f16x8 a1 = *(const f16x8*)(bp + 512);
  f16x8 a2 = *(const f16x8*)(bp + 1024);
  f16x8 b0v = *(const f16x8*)(bp + 1536);
  f16x8 b1v = *(const f16x8*)(bp + 1536 + 512);
  f16x8 b2v = *(const f16x8*)(bp + 1536 + 1024);
  bp += 3072;

  int curBJ = -1;
  for (int pp = ppStart; pp < ppEnd; ++pp){
    const int bJ = PB_BJ[pp];
    if (bJ != curBJ){
      curBJ = bJ;
      #pragma unroll
      for (int q = 0; q < 8; ++q)
        FeT[q] = *(const f16x8*)&sG[btl][((bJ << 3) + q) ^ btSw][0];
      f16x8 mr = *(const f16x8*)&sMu[btl][((bJ ^ btSw) << 3)];
      #pragma unroll
      for (int q = 0; q < 8; ++q) mue[q] = (float)mr[q];
    }
    const int bIn = PB_BI[pp + 1];
    // ---- even chunk (stage A), refill with next pair's p=0 ----
    {
      f16x8 af;
      BUILD(af, fdA, mudA);
      MFMA3(af, a0, a1, a2);
      a0 = *(const f16x8*)(bp);
      a1 = *(const f16x8*)(bp + 512);
      a2 = *(const f16x8*)(bp + 1024);
      const int dn = bIn * 8 + g;
      fdA = *(const f16x8*)&sG[btl][dn ^ btSw][0];
      mudA = (float)sMu[btl][((bIn ^ btSw) << 3) | g];
    }
    // ---- odd chunk (stage B), refill with next pair's p=1 ----
    {
      f16x8 af;
      BUILD(af, fdB, mudB);
      MFMA3(af, b0v, b1v, b2v);
      b0v = *(const f16x8*)(bp + 1536);
      b1v = *(const f16x8*)(bp + 1536 + 512);
      b2v = *(const f16x8*)(bp + 1536 + 1024);
      const int dn = bIn * 8 + 4 + g;
      fdB = *(const f16x8*)&sG[btl][dn ^ btSw][0];
      mudB = (float)sMu[btl][((bIn ^ btSw) << 3) | (4 + g)];
    }
    bp += 3072;
  }

  // ---- ext chunks (wave 1 only), ABSOLUTE addressing at chunk 72 ----
  if (xh == 1){
    const f16* bpe = BG + (size_t)72 * 1536 + (size_t)(kc * 4 + g) * 8;
    #pragma unroll
    for (int m = 0; m < 2; ++m){
      f16x8 af = *(const f16x8*)&sMu[btl][(((m * 4 + g) ^ btSw) << 3)];
      f16x8 e0 = *(const f16x8*)(bpe);
      f16x8 e1 = *(const f16x8*)(bpe + 512);
      f16x8 e2 = *(const f16x8*)(bpe + 1024);
      MFMA3(af, e0, e1, e2);
      bpe += 1536;
    }
    const float* vr0 = var_t + (size_t)(bt0 + btl) * 64;
    #pragma unroll
    for (int m = 0; m < 2; ++m){
      const float* vr = vr0 + m * 32 + g * 8;
      f32x4 va = *(const f32x4*)(vr);
      f32x4 vb = *(const f32x4*)(vr + 4);
      f16x8 af;
      #pragma unroll
      for (int r = 0; r < 4; ++r){ af[r] = (f16)va[r]; af[4 + r] = (f16)vb[r]; }
      f16x8 e0 = *(const f16x8*)(bpe);
      f16x8 e1 = *(const f16x8*)(bpe + 512);
      f16x8 e2 = *(const f16x8*)(bpe + 1024);
      MFMA3(af, e0, e1, e2);
      bpe += 1536;
    }
  }

  // ---- cross-wave reduce (aliased into sG after barrier) ----
  __syncthreads();                         // all waves done reading sG/sMu
  float* sRedF = (float*)sG;               // [64][13] floats = 3328 B
  if (xh == 1){
    const int bofs = l * 13;
    #pragma unroll
    for (int r = 0; r < 4; ++r){
      sRedF[bofs + r]     = acc0[r];
      sRedF[bofs + 4 + r] = acc1[r];
      sRedF[bofs + 8 + r] = acc2[r];
    }
  }
  __syncthreads();
  if (xh == 0){
    const int bofs = l * 13;
    #pragma unroll
    for (int r = 0; r < 4; ++r){
      acc0[r] += sRedF[bofs + r];
      acc1[r] += sRedF[bofs + 4 + r];
      acc2[r] += sRedF[bofs + 8 + r];
    }
    float c0a = c0o[kc];
    float c0b = c0o[16 + kc];
    float c0c = c0o[32];
    #pragma unroll
    for (int reg = 0; reg < 4; ++reg){
      int obt = bt0 + g * 4 + reg;
      bool mk = byteMask ? (maskb[obt] != 0) : (maskb[(size_t)4 * obt] != 0);
      float* op = out + (size_t)obt * 33;
      op[kc]      = mk ? fmaf(-0.5f, acc0[reg], c0a) : 0.f;
      op[16 + kc] = mk ? fmaf(-0.5f, acc1[reg], c0b) : 0.f;
      if (kc == 0) op[32] = mk ? fmaf(-0.5f, acc2[reg], c0c) : 0.f;
    }
  }
}

// --------------------------- launch -----------------------------------------
extern "C" void kernel_launch(void* const* d_in, const int* in_sizes, int n_in,
                              void* d_out, int out_size, void* d_ws, size_t ws_size,
                              hipStream_t stream)
{
  const float* mu_t  = (const float*)d_in[0];
  const float* var_t = (const float*)d_in[1];
  const float* F_t   = (const float*)d_in[2];
  const float* mu_k  = (const float*)d_in[3];
  const float* Psi   = (const float*)d_in[4];
  const float* nu    = (const float*)d_in[5];
  const float* kap   = (const float*)d_in[6];
  const unsigned char* mask = (const unsigned char*)d_in[7];

  f16*   BG  = (f16*)d_ws;                      // 76*3*64*8 f16 = 233472 B
  float* c0o = (float*)((char*)d_ws + (size_t)NCHUNK * 3 * 64 * 8 * 2);
  float* outp = (float*)d_out;

  hipLaunchKernelGGL(prep_kernel, dim3(48), dim3(256), 0, stream,
                     mu_k, Psi, nu, kap, BG, c0o);
  hipLaunchKernelGGL(main_kernel, dim3(BT_TOTAL / BT_BLK), dim3(128), 0, stream,
                     mu_t, var_t, F_t, mask, BG, c0o, outp);
}